// Round 11
// baseline (388.451 us; speedup 1.0000x reference)
//
#include <hip/hip_runtime.h>
#include <cfloat>

#define KC 512        // codes
#define DD 64         // dim
#define HW 4096       // 64*64
#define NPIX 131072   // 32*64*64
#define QSIZE 8388608 // 32*64*64*64
#define PXB 128       // pixels per tile
#define NTILE (NPIX / PXB)   // 1024 tiles
#define NBLK (NTILE / 2)     // 512 persistent blocks, 2 tiles each
#define NTH 512       // 8 waves
#define MARGIN 4.0e-3f  // >6x worst-case screen-vs-np error bound

typedef short short8 __attribute__((ext_vector_type(8)));   // 8 bf16 MFMA operand
typedef float f32x4 __attribute__((ext_vector_type(4)));
typedef float nfloat4 __attribute__((ext_vector_type(4)));
typedef unsigned long long u64;

__device__ __forceinline__ unsigned short bf16_rne(float f) {
    unsigned int u = __float_as_uint(f);
    u += 0x7FFFu + ((u >> 16) & 1u);
    return (unsigned short)(u >> 16);
}

// LDS-only barrier: syncs waves + orders DS ops without draining vmcnt —
// in-flight NT output stores keep streaming across it.
__device__ __forceinline__ void barrier_lds_only() {
    asm volatile("s_waitcnt lgkmcnt(0)" ::: "memory");
    __builtin_amdgcn_s_barrier();
    __builtin_amdgcn_sched_barrier(0);
}

// Full-drain barrier: all VMEM (incl. NT stores) + DS retired, then barrier.
// Used to order enc zero-fills before their ones-scatters; placed so the
// zeros have had a full compute phase to drain -> wait ~0.
__device__ __forceinline__ void barrier_full_drain() {
    asm volatile("s_waitcnt vmcnt(0) lgkmcnt(0)" ::: "memory");
    __builtin_amdgcn_s_barrier();
    __builtin_amdgcn_sched_barrier(0);
}

// --- prep (once per launch, validated R10): swizzled bf16 B-frag codebook
// (64 KB) + np-pairwise w2. Slot s=(ct*2+kc)*64+ln holds
// w[ct*16+(ln&15)][kc*32+(ln>>4)*8 .. +8) as bf16x8.
__global__ __launch_bounds__(1024) void prep(
    const float* __restrict__ w, float* __restrict__ w2g,
    uint4* __restrict__ wswz) {
  const int gt = blockIdx.x * 1024 + threadIdx.x;   // 0..4095
  {
    int ct = gt >> 7, kc = (gt >> 6) & 1, ln = gt & 63;
    int n = ln & 15, q = ln >> 4;
    const float* wp = w + (ct * 16 + n) * DD + kc * 32 + q * 8;
    nfloat4 f0 = *(const nfloat4*)(wp);
    nfloat4 f1 = *(const nfloat4*)(wp + 4);
    uint4 u;
    u.x = (unsigned)bf16_rne(f0[0]) | ((unsigned)bf16_rne(f0[1]) << 16);
    u.y = (unsigned)bf16_rne(f0[2]) | ((unsigned)bf16_rne(f0[3]) << 16);
    u.z = (unsigned)bf16_rne(f1[0]) | ((unsigned)bf16_rne(f1[1]) << 16);
    u.w = (unsigned)bf16_rne(f1[2]) | ((unsigned)bf16_rne(f1[3]) << 16);
    wswz[gt] = u;
  }
  if (gt < KC) {      // w2g[k]: numpy-pairwise fp32 sum of squares
    const float* wk = w + gt * DD;
    float r0 = __fmul_rn(wk[0], wk[0]), r1 = __fmul_rn(wk[1], wk[1]),
          r2 = __fmul_rn(wk[2], wk[2]), r3 = __fmul_rn(wk[3], wk[3]),
          r4 = __fmul_rn(wk[4], wk[4]), r5 = __fmul_rn(wk[5], wk[5]),
          r6 = __fmul_rn(wk[6], wk[6]), r7 = __fmul_rn(wk[7], wk[7]);
    #pragma unroll
    for (int i = 8; i < DD; i += 8) {
      r0 = __fadd_rn(r0, __fmul_rn(wk[i+0], wk[i+0]));
      r1 = __fadd_rn(r1, __fmul_rn(wk[i+1], wk[i+1]));
      r2 = __fadd_rn(r2, __fmul_rn(wk[i+2], wk[i+2]));
      r3 = __fadd_rn(r3, __fmul_rn(wk[i+3], wk[i+3]));
      r4 = __fadd_rn(r4, __fmul_rn(wk[i+4], wk[i+4]));
      r5 = __fadd_rn(r5, __fmul_rn(wk[i+5], wk[i+5]));
      r6 = __fadd_rn(r6, __fmul_rn(wk[i+6], wk[i+6]));
      r7 = __fadd_rn(r7, __fmul_rn(wk[i+7], wk[i+7]));
    }
    w2g[gt] = __fadd_rn(__fadd_rn(__fadd_rn(r0, r1), __fadd_rn(r2, r3)),
                        __fadd_rn(__fadd_rn(r4, r5), __fadd_rn(r6, r7)));
  }
}

// ======== per-tile phase helpers (bodies identical to R0/R4's kernel) ====

__device__ __forceinline__ void tile_prelude(
    const float* __restrict__ xt, float* Xs, u64 (*candm)[8],
    short8& a0, short8& a1, int tid, int lane, int wv) {
  ((u64*)candm)[tid] = 0;
  ((u64*)candm)[tid + NTH] = 0;
  if (tid < PXB) {
    const float* xp = xt + tid;
    float r0 = __fmul_rn(xp[0*HW], xp[0*HW]), r1 = __fmul_rn(xp[1*HW], xp[1*HW]),
          r2 = __fmul_rn(xp[2*HW], xp[2*HW]), r3 = __fmul_rn(xp[3*HW], xp[3*HW]),
          r4 = __fmul_rn(xp[4*HW], xp[4*HW]), r5 = __fmul_rn(xp[5*HW], xp[5*HW]),
          r6 = __fmul_rn(xp[6*HW], xp[6*HW]), r7 = __fmul_rn(xp[7*HW], xp[7*HW]);
    #pragma unroll
    for (int i = 8; i < DD; i += 8) {
      r0 = __fadd_rn(r0, __fmul_rn(xp[(size_t)(i+0)*HW], xp[(size_t)(i+0)*HW]));
      r1 = __fadd_rn(r1, __fmul_rn(xp[(size_t)(i+1)*HW], xp[(size_t)(i+1)*HW]));
      r2 = __fadd_rn(r2, __fmul_rn(xp[(size_t)(i+2)*HW], xp[(size_t)(i+2)*HW]));
      r3 = __fadd_rn(r3, __fmul_rn(xp[(size_t)(i+3)*HW], xp[(size_t)(i+3)*HW]));
      r4 = __fadd_rn(r4, __fmul_rn(xp[(size_t)(i+4)*HW], xp[(size_t)(i+4)*HW]));
      r5 = __fadd_rn(r5, __fmul_rn(xp[(size_t)(i+5)*HW], xp[(size_t)(i+5)*HW]));
      r6 = __fadd_rn(r6, __fmul_rn(xp[(size_t)(i+6)*HW], xp[(size_t)(i+6)*HW]));
      r7 = __fadd_rn(r7, __fmul_rn(xp[(size_t)(i+7)*HW], xp[(size_t)(i+7)*HW]));
    }
    Xs[tid] = __fadd_rn(__fadd_rn(__fadd_rn(r0, r1), __fadd_rn(r2, r3)),
                        __fadd_rn(__fadd_rn(r4, r5), __fadd_rn(r6, r7)));
  }
  const int am = lane & 15, aq = lane >> 4;
  const float* xa = xt + wv * 16 + am;
  #pragma unroll
  for (int j = 0; j < 8; ++j) {
    a0[j] = (short)bf16_rne(-2.0f * xa[(size_t)(aq * 8 + j) * HW]);
    a1[j] = (short)bf16_rne(-2.0f * xa[(size_t)(32 + aq * 8 + j) * HW]);
  }
}

__device__ __forceinline__ void tile_screen(
    const short8* wl8, const float* w2s, u64 (*candm)[8],
    short8 a0, short8 a1, int lane, int wv) {
  const int cn = lane & 15;
  // pass 1: per-pixel min of screened S over 512 codes
  // C layout (m89-verified): col=lane&15, row=(lane>>4)*4+reg
  float m0 = FLT_MAX, m1 = FLT_MAX, m2 = FLT_MAX, m3 = FLT_MAX;
  for (int ct = 0; ct < 32; ++ct) {
    float wk2 = w2s[ct * 16 + cn];
    f32x4 acc = {wk2, wk2, wk2, wk2};
    acc = __builtin_amdgcn_mfma_f32_16x16x32_bf16(a0, wl8[ct * 128 + lane], acc, 0, 0, 0);
    acc = __builtin_amdgcn_mfma_f32_16x16x32_bf16(a1, wl8[ct * 128 + 64 + lane], acc, 0, 0, 0);
    m0 = fminf(m0, acc[0]); m1 = fminf(m1, acc[1]);
    m2 = fminf(m2, acc[2]); m3 = fminf(m3, acc[3]);
  }
  #pragma unroll
  for (int s = 1; s < 16; s <<= 1) {
    m0 = fminf(m0, __shfl_xor(m0, s));
    m1 = fminf(m1, __shfl_xor(m1, s));
    m2 = fminf(m2, __shfl_xor(m2, s));
    m3 = fminf(m3, __shfl_xor(m3, s));
  }
  const float t0 = m0 + MARGIN, t1 = m1 + MARGIN,
              t2 = m2 + MARGIN, t3 = m3 + MARGIN;
  // pass 2: flag candidates into per-pixel bitmasks
  for (int ct = 0; ct < 32; ++ct) {
    float wk2 = w2s[ct * 16 + cn];
    f32x4 acc = {wk2, wk2, wk2, wk2};
    acc = __builtin_amdgcn_mfma_f32_16x16x32_bf16(a0, wl8[ct * 128 + lane], acc, 0, 0, 0);
    acc = __builtin_amdgcn_mfma_f32_16x16x32_bf16(a1, wl8[ct * 128 + 64 + lane], acc, 0, 0, 0);
    u64 bm0 = __ballot(acc[0] <= t0);
    u64 bm1 = __ballot(acc[1] <= t1);
    u64 bm2 = __ballot(acc[2] <= t2);
    u64 bm3 = __ballot(acc[3] <= t3);
    if (lane < 4) {   // lane r owns reg r; ballot bit (q*16+n) -> pixel q*4+r, code ct*16+n
      u64 mk = (lane == 0) ? bm0 : (lane == 1) ? bm1 : (lane == 2) ? bm2 : bm3;
      int word = ct >> 2, sh = (ct & 3) * 16;
      #pragma unroll
      for (int q = 0; q < 4; ++q) {
        u64 bits = (mk >> (q * 16)) & 0xFFFFull;
        if (bits) candm[wv * 16 + q * 4 + lane][word] |= bits << sh;
      }
    }
  }
}

__device__ __forceinline__ void tile_refine(
    const float* __restrict__ xt, const float* __restrict__ w,
    const float* w2s, const float* Xs, const u64 (*candm)[8],
    int* sidx, float* __restrict__ out_idx, int bix, int tid, int lane) {
  const int px = tid >> 2, part = tid & 3;
  const float X = Xs[px];
  const float* xr = xt + px;
  float bestd = FLT_MAX; int bk = 1 << 30;
  for (int wd = part * 2; wd < part * 2 + 2; ++wd) {
    u64 msk = candm[px][wd];
    while (msk) {
      int bit = __ffsll((unsigned long long)msk) - 1;
      msk &= msk - 1;
      int k = wd * 64 + bit;
      const float* wp = w + k * DD;
      float P = 0.f;                       // ascending-d fma chain (BLAS order)
      #pragma unroll
      for (int dc = 0; dc < 16; ++dc) {
        nfloat4 w4 = *(const nfloat4*)(wp + dc * 4);
        P = __fmaf_rn(xr[(size_t)(dc * 4 + 0) * HW], w4[0], P);
        P = __fmaf_rn(xr[(size_t)(dc * 4 + 1) * HW], w4[1], P);
        P = __fmaf_rn(xr[(size_t)(dc * 4 + 2) * HW], w4[2], P);
        P = __fmaf_rn(xr[(size_t)(dc * 4 + 3) * HW], w4[3], P);
      }
      float dist = __fsub_rn(__fadd_rn(X, w2s[k]), __fadd_rn(P, P));
      if (dist < bestd || (dist == bestd && k < bk)) { bestd = dist; bk = k; }
    }
  }
  float od = __shfl_down(bestd, 1); int ok = __shfl_down(bk, 1);
  if ((lane & 3) < 3 && (od < bestd || (od == bestd && ok < bk))) { bestd = od; bk = ok; }
  od = __shfl_down(bestd, 2); ok = __shfl_down(bk, 2);
  if ((lane & 3) < 2 && (od < bestd || (od == bestd && ok < bk))) { bestd = od; bk = ok; }
  if (part == 0) {
    sidx[px] = bk;
    out_idx[bix * PXB + px] = (float)bk;
  }
}

__device__ __forceinline__ float tile_quant(
    const float* __restrict__ xt, const float* __restrict__ w,
    const int* sidx, float* __restrict__ qb, int tid) {
  float lsum = 0.f;
  for (int i = tid; i < PXB * DD; i += NTH) {   // 16 iters
    int d = i >> 7, pp = i & 127;
    float qv = w[sidx[pp] * DD + d];      // L1/L2-resident gather
    float dv = qv - xt[(size_t)d * HW + pp];
    lsum = __fmaf_rn(dv, dv, lsum);
    __builtin_nontemporal_store(qv, qb + (size_t)d * HW + pp);
  }
  return lsum;
}

__device__ __forceinline__ void tile_enc(
    const int* sidx, float* __restrict__ basep, int tid) {
  // fused one-hot enc (base ≡ 1 mod 4 floats: 3-head, aligned body, 1-tail)
  for (int t = tid; t < 16383; t += NTH) {
    int u = 3 + 4 * t;
    nfloat4 v;
    #pragma unroll
    for (int j = 0; j < 4; ++j) {
      int e = u + j;
      v[j] = (sidx[e >> 9] == (e & 511)) ? 1.0f : 0.0f;
    }
    __builtin_nontemporal_store(v, (nfloat4*)(basep + u));
  }
  if (tid < 3) basep[tid] = (sidx[0] == tid) ? 1.0f : 0.0f;
  else if (tid == 3) basep[PXB * KC - 1] = (sidx[127] == 511) ? 1.0f : 0.0f;
}

__device__ __forceinline__ void enc_zero_fill(float* __restrict__ basep, int tid) {
  // zero the 65536-float enc region (base ≡ 1 mod 4: 3-head, body, 1-tail)
  const nfloat4 z = {0.f, 0.f, 0.f, 0.f};
  if (tid < 3) __builtin_nontemporal_store(0.0f, basep + tid);
  else if (tid == 3) __builtin_nontemporal_store(0.0f, basep + PXB * KC - 1);
  for (int t = tid; t < 16383; t += NTH)
    __builtin_nontemporal_store(z, (nfloat4*)(basep + 3 + 4 * t));
}

// --- main R21: symmetrized checkerboard (best base R10 = 372.5 µs). Neither
// mode writes a full enc at the kernel tail anymore:
//   mode0: enc-A fused at the A/B boundary + enc-B ZEROS at the boundary,
//          scatter-B ones at the tail.
//   mode1: enc-A+B zeros up front, scatter-A at the boundary, scatter-B tail.
// The kernel-end exposed drain shrinks from ~320 KB/CU (mode0's fused enc-B)
// to ~65 KB/CU (scatters+quant-B) — the last ~10 µs of serial enc drain
// before kernel retirement disappears. Zeros-before-ones ordering: mode1 via
// the post-refine-A full-drain (R10, wait ~0); mode0's zero-B via a
// post-refine-B full-drain (zeros had all of screen-B+refine-B to drain).
// Outputs byte-identical; numerics untouched.
__global__ __launch_bounds__(NTH, 4) void vq_fused(
    const float* __restrict__ x, const float* __restrict__ w,
    const float* __restrict__ w2g, const uint4* __restrict__ wswz,
    float* __restrict__ out_q, float* __restrict__ out_enc,
    float* __restrict__ out_idx, double* __restrict__ partial) {

  __shared__ uint4 wlds[4096];        // 64 KB: B-frags, slot=(ct*2+kc)*64+lane
  __shared__ float w2s[KC];           // 2 KB: np-exact ||w_k||^2
  __shared__ u64 candm[PXB][8];       // 8 KB: 512-bit candidate mask per pixel
  __shared__ float Xs[PXB];           // np-exact ||x||^2 per pixel
  __shared__ int sidx[PXB];
  __shared__ float sredf[8];

  const int tid = threadIdx.x;
  const int lane = tid & 63;
  const int wv = tid >> 6;            // wave 0..7, each owns 16 pixels
  const int mode = (blockIdx.x >> 8) & 1;   // co-resident pair {i, i+256} mixed

  // tile A = blockIdx.x, tile B = blockIdx.x + 512
  const int bix0 = blockIdx.x;
  const int b0 = bix0 >> 5;
  const int q0 = (bix0 & 31) * PXB;
  const float* xt0 = x + (size_t)b0 * (DD * HW) + q0;
  const int bix1 = blockIdx.x + NBLK;
  const int b1 = bix1 >> 5;
  const int q1 = (bix1 & 31) * PXB;
  const float* xt1 = x + (size_t)b1 * (DD * HW) + q1;
  float* bp0 = out_enc + (size_t)bix0 * (PXB * KC);
  float* bp1 = out_enc + (size_t)bix1 * (PXB * KC);

  // ---- stage prebuilt codebook ONCE (serves both tiles) ----
  #pragma unroll
  for (int s = 0; s < 8; ++s) wlds[tid + s * NTH] = wswz[tid + s * NTH];
  w2s[tid] = w2g[tid];   // KC == NTH

  short8 a0, a1;
  tile_prelude(xt0, Xs, candm, a0, a1, tid, lane, wv);
  if (mode) {            // mode1: front-load both tiles' enc zeros (in flight)
    enc_zero_fill(bp0, tid);
    enc_zero_fill(bp1, tid);
    barrier_lds_only();  // staging needs DS-visibility only; zeros NOT drained
  } else {
    __syncthreads();     // mode0: nothing outstanding anyway
  }

  const short8* wl8 = (const short8*)wlds;

  // ================= TILE A =================
  tile_screen(wl8, w2s, candm, a0, a1, lane, wv);
  barrier_lds_only();    // candm-A ready
  tile_refine(xt0, w, w2s, Xs, candm, sidx, out_idx, bix0, tid, lane);
  if (mode) {
    barrier_full_drain(); // zeros (both tiles) retired — drained in background
                          // under screen-A+refine-A; wait here ~0. Orders
                          // zeros before BOTH ones-scatters.
  } else {
    barrier_lds_only();   // sidx-A ready
  }

  // ---- A/B boundary: prelude-B loads FIRST, then the A-output store burst
  // (+ mode0's enc-B zero-fill) which drains under screen-B/refine-B. ----
  tile_prelude(xt1, Xs, candm, a0, a1, tid, lane, wv);
  if (mode) {            // ones-scatter over drained zeros
    if (tid < PXB)
      __builtin_nontemporal_store(1.0f, bp0 + tid * KC + sidx[tid]);
  }
  {
    float lsum = tile_quant(xt0, w, sidx, out_q + (size_t)b0 * (DD * HW) + q0, tid);
    #pragma unroll
    for (int off = 32; off > 0; off >>= 1) lsum += __shfl_down(lsum, off);
    if (lane == 0) sredf[wv] = lsum;
  }
  if (!mode) {
    tile_enc(sidx, bp0, tid);     // enc-A fused (zeros+ones)
    enc_zero_fill(bp1, tid);      // enc-B zeros issued NOW; drain under B-compute
  }
  barrier_lds_only();    // sredf/Xs-B/candm-B ready; A stores stay in flight
  if (tid == 0) {
    double t = 0.0;
    #pragma unroll
    for (int i = 0; i < 8; ++i) t += (double)sredf[i];
    partial[bix0] = t;
  }

  // ================= TILE B =================
  tile_screen(wl8, w2s, candm, a0, a1, lane, wv);   // boundary stores drain here
  barrier_lds_only();    // candm-B ready
  tile_refine(xt1, w, w2s, Xs, candm, sidx, out_idx, bix1, tid, lane);
  barrier_full_drain();  // sidx-B ready AND all enc-B zeros retired (issued a
                         // full compute phase ago -> wait ~0); orders zeros
                         // before the tail scatter for BOTH modes.

  // ---- tail: only tiny writes remain (both modes) ----
  if (tid < PXB)
    __builtin_nontemporal_store(1.0f, bp1 + tid * KC + sidx[tid]);
  {
    float lsum = tile_quant(xt1, w, sidx, out_q + (size_t)b1 * (DD * HW) + q1, tid);
    #pragma unroll
    for (int off = 32; off > 0; off >>= 1) lsum += __shfl_down(lsum, off);
    if (lane == 0) sredf[wv] = lsum;
  }
  barrier_lds_only();    // sredf-B ready
  if (tid == 0) {
    double t = 0.0;
    #pragma unroll
    for (int i = 0; i < 8; ++i) t += (double)sredf[i];
    partial[bix1] = t;
  }
  // kernel end: only ~65 KB/CU (scatter+quant-B) left to drain
}

// --- epilogue: loss = vq + commit = 2 * mean((q - x)^2) ---
__global__ void finish_kernel(const double* __restrict__ partial,
                              float* __restrict__ out) {
  int t = threadIdx.x;   // 256 threads, 1024 partials
  double s = partial[t] + partial[t + 256] + partial[t + 512] + partial[t + 768];
  #pragma unroll
  for (int off = 32; off > 0; off >>= 1) s += __shfl_down(s, off);
  __shared__ double sr[4];
  if ((t & 63) == 0) sr[t >> 6] = s;
  __syncthreads();
  if (t == 0)
    out[0] = (float)(2.0 * (sr[0] + sr[1] + sr[2] + sr[3]) / (double)QSIZE);
}

extern "C" void kernel_launch(void* const* d_in, const int* in_sizes, int n_in,
                              void* d_out, int out_size, void* d_ws, size_t ws_size,
                              hipStream_t stream) {
  const float* x = (const float*)d_in[0];   // [32,64,64,64] f32 NCHW
  const float* w = (const float*)d_in[1];   // [512,64] f32
  float* out = (float*)d_out;
  float* out_q = out + 1;
  float* out_enc = out_q + QSIZE;
  float* out_idx = out_enc + (size_t)NPIX * KC;

  // d_ws layout: partial[1024] @0 (8 KB) | w2g[512] @8192 | wswz[4096] @16384
  double* partial = (double*)d_ws;
  float* w2g = (float*)((char*)d_ws + 8192);
  uint4* wswz = (uint4*)((char*)d_ws + 16384);

  prep<<<4, 1024, 0, stream>>>(w, w2g, wswz);
  vq_fused<<<NBLK, NTH, 0, stream>>>(x, w, w2g, wswz, out_q, out_enc, out_idx, partial);
  finish_kernel<<<1, 256, 0, stream>>>(partial, out);
}

// Round 12
// 374.315 us; speedup vs baseline: 1.0378x; 1.0378x over previous
//
#include <hip/hip_runtime.h>
#include <cfloat>

#define KC 512        // codes
#define DD 64         // dim
#define HW 4096       // 64*64
#define NPIX 131072   // 32*64*64
#define QSIZE 8388608 // 32*64*64*64
#define PXB 128       // pixels per tile
#define NTILE (NPIX / PXB)   // 1024 tiles
#define NBLK (NTILE / 2)     // 512 persistent blocks, 2 tiles each
#define NTH 512       // 8 waves
#define MARGIN 4.0e-3f  // >6x worst-case screen-vs-np error bound

typedef short short8 __attribute__((ext_vector_type(8)));   // 8 bf16 MFMA operand
typedef float f32x4 __attribute__((ext_vector_type(4)));
typedef float nfloat4 __attribute__((ext_vector_type(4)));
typedef unsigned long long u64;

__device__ __forceinline__ unsigned short bf16_rne(float f) {
    unsigned int u = __float_as_uint(f);
    u += 0x7FFFu + ((u >> 16) & 1u);
    return (unsigned short)(u >> 16);
}

// LDS-only barrier: syncs waves + orders DS ops without draining vmcnt —
// in-flight NT output stores keep streaming across it.
__device__ __forceinline__ void barrier_lds_only() {
    asm volatile("s_waitcnt lgkmcnt(0)" ::: "memory");
    __builtin_amdgcn_s_barrier();
    __builtin_amdgcn_sched_barrier(0);
}

// Full-drain barrier: all VMEM (incl. NT stores) + DS retired, then barrier.
// Used by mode1 ONCE, post-refine-A, to order enc zeros before ones-scatters.
__device__ __forceinline__ void barrier_full_drain() {
    asm volatile("s_waitcnt vmcnt(0) lgkmcnt(0)" ::: "memory");
    __builtin_amdgcn_s_barrier();
    __builtin_amdgcn_sched_barrier(0);
}

// --- prep (once per launch, validated R10): swizzled bf16 B-frag codebook
// (64 KB) + np-pairwise w2. Slot s=(ct*2+kc)*64+ln holds
// w[ct*16+(ln&15)][kc*32+(ln>>4)*8 .. +8) as bf16x8.
__global__ __launch_bounds__(1024) void prep(
    const float* __restrict__ w, float* __restrict__ w2g,
    uint4* __restrict__ wswz) {
  const int gt = blockIdx.x * 1024 + threadIdx.x;   // 0..4095
  {
    int ct = gt >> 7, kc = (gt >> 6) & 1, ln = gt & 63;
    int n = ln & 15, q = ln >> 4;
    const float* wp = w + (ct * 16 + n) * DD + kc * 32 + q * 8;
    nfloat4 f0 = *(const nfloat4*)(wp);
    nfloat4 f1 = *(const nfloat4*)(wp + 4);
    uint4 u;
    u.x = (unsigned)bf16_rne(f0[0]) | ((unsigned)bf16_rne(f0[1]) << 16);
    u.y = (unsigned)bf16_rne(f0[2]) | ((unsigned)bf16_rne(f0[3]) << 16);
    u.z = (unsigned)bf16_rne(f1[0]) | ((unsigned)bf16_rne(f1[1]) << 16);
    u.w = (unsigned)bf16_rne(f1[2]) | ((unsigned)bf16_rne(f1[3]) << 16);
    wswz[gt] = u;
  }
  if (gt < KC) {      // w2g[k]: numpy-pairwise fp32 sum of squares
    const float* wk = w + gt * DD;
    float r0 = __fmul_rn(wk[0], wk[0]), r1 = __fmul_rn(wk[1], wk[1]),
          r2 = __fmul_rn(wk[2], wk[2]), r3 = __fmul_rn(wk[3], wk[3]),
          r4 = __fmul_rn(wk[4], wk[4]), r5 = __fmul_rn(wk[5], wk[5]),
          r6 = __fmul_rn(wk[6], wk[6]), r7 = __fmul_rn(wk[7], wk[7]);
    #pragma unroll
    for (int i = 8; i < DD; i += 8) {
      r0 = __fadd_rn(r0, __fmul_rn(wk[i+0], wk[i+0]));
      r1 = __fadd_rn(r1, __fmul_rn(wk[i+1], wk[i+1]));
      r2 = __fadd_rn(r2, __fmul_rn(wk[i+2], wk[i+2]));
      r3 = __fadd_rn(r3, __fmul_rn(wk[i+3], wk[i+3]));
      r4 = __fadd_rn(r4, __fmul_rn(wk[i+4], wk[i+4]));
      r5 = __fadd_rn(r5, __fmul_rn(wk[i+5], wk[i+5]));
      r6 = __fadd_rn(r6, __fmul_rn(wk[i+6], wk[i+6]));
      r7 = __fadd_rn(r7, __fmul_rn(wk[i+7], wk[i+7]));
    }
    w2g[gt] = __fadd_rn(__fadd_rn(__fadd_rn(r0, r1), __fadd_rn(r2, r3)),
                        __fadd_rn(__fadd_rn(r4, r5), __fadd_rn(r6, r7)));
  }
}

// ======== per-tile phase helpers (bodies identical to R0/R4's kernel) ====

__device__ __forceinline__ void tile_prelude(
    const float* __restrict__ xt, float* Xs, u64 (*candm)[8],
    short8& a0, short8& a1, int tid, int lane, int wv) {
  ((u64*)candm)[tid] = 0;
  ((u64*)candm)[tid + NTH] = 0;
  if (tid < PXB) {
    const float* xp = xt + tid;
    float r0 = __fmul_rn(xp[0*HW], xp[0*HW]), r1 = __fmul_rn(xp[1*HW], xp[1*HW]),
          r2 = __fmul_rn(xp[2*HW], xp[2*HW]), r3 = __fmul_rn(xp[3*HW], xp[3*HW]),
          r4 = __fmul_rn(xp[4*HW], xp[4*HW]), r5 = __fmul_rn(xp[5*HW], xp[5*HW]),
          r6 = __fmul_rn(xp[6*HW], xp[6*HW]), r7 = __fmul_rn(xp[7*HW], xp[7*HW]);
    #pragma unroll
    for (int i = 8; i < DD; i += 8) {
      r0 = __fadd_rn(r0, __fmul_rn(xp[(size_t)(i+0)*HW], xp[(size_t)(i+0)*HW]));
      r1 = __fadd_rn(r1, __fmul_rn(xp[(size_t)(i+1)*HW], xp[(size_t)(i+1)*HW]));
      r2 = __fadd_rn(r2, __fmul_rn(xp[(size_t)(i+2)*HW], xp[(size_t)(i+2)*HW]));
      r3 = __fadd_rn(r3, __fmul_rn(xp[(size_t)(i+3)*HW], xp[(size_t)(i+3)*HW]));
      r4 = __fadd_rn(r4, __fmul_rn(xp[(size_t)(i+4)*HW], xp[(size_t)(i+4)*HW]));
      r5 = __fadd_rn(r5, __fmul_rn(xp[(size_t)(i+5)*HW], xp[(size_t)(i+5)*HW]));
      r6 = __fadd_rn(r6, __fmul_rn(xp[(size_t)(i+6)*HW], xp[(size_t)(i+6)*HW]));
      r7 = __fadd_rn(r7, __fmul_rn(xp[(size_t)(i+7)*HW], xp[(size_t)(i+7)*HW]));
    }
    Xs[tid] = __fadd_rn(__fadd_rn(__fadd_rn(r0, r1), __fadd_rn(r2, r3)),
                        __fadd_rn(__fadd_rn(r4, r5), __fadd_rn(r6, r7)));
  }
  const int am = lane & 15, aq = lane >> 4;
  const float* xa = xt + wv * 16 + am;
  #pragma unroll
  for (int j = 0; j < 8; ++j) {
    a0[j] = (short)bf16_rne(-2.0f * xa[(size_t)(aq * 8 + j) * HW]);
    a1[j] = (short)bf16_rne(-2.0f * xa[(size_t)(32 + aq * 8 + j) * HW]);
  }
}

__device__ __forceinline__ void tile_screen(
    const short8* wl8, const float* w2s, u64 (*candm)[8],
    short8 a0, short8 a1, int lane, int wv) {
  const int cn = lane & 15;
  // pass 1: per-pixel min of screened S over 512 codes
  // C layout (m89-verified): col=lane&15, row=(lane>>4)*4+reg
  float m0 = FLT_MAX, m1 = FLT_MAX, m2 = FLT_MAX, m3 = FLT_MAX;
  for (int ct = 0; ct < 32; ++ct) {
    float wk2 = w2s[ct * 16 + cn];
    f32x4 acc = {wk2, wk2, wk2, wk2};
    acc = __builtin_amdgcn_mfma_f32_16x16x32_bf16(a0, wl8[ct * 128 + lane], acc, 0, 0, 0);
    acc = __builtin_amdgcn_mfma_f32_16x16x32_bf16(a1, wl8[ct * 128 + 64 + lane], acc, 0, 0, 0);
    m0 = fminf(m0, acc[0]); m1 = fminf(m1, acc[1]);
    m2 = fminf(m2, acc[2]); m3 = fminf(m3, acc[3]);
  }
  #pragma unroll
  for (int s = 1; s < 16; s <<= 1) {
    m0 = fminf(m0, __shfl_xor(m0, s));
    m1 = fminf(m1, __shfl_xor(m1, s));
    m2 = fminf(m2, __shfl_xor(m2, s));
    m3 = fminf(m3, __shfl_xor(m3, s));
  }
  const float t0 = m0 + MARGIN, t1 = m1 + MARGIN,
              t2 = m2 + MARGIN, t3 = m3 + MARGIN;
  // pass 2: flag candidates into per-pixel bitmasks
  for (int ct = 0; ct < 32; ++ct) {
    float wk2 = w2s[ct * 16 + cn];
    f32x4 acc = {wk2, wk2, wk2, wk2};
    acc = __builtin_amdgcn_mfma_f32_16x16x32_bf16(a0, wl8[ct * 128 + lane], acc, 0, 0, 0);
    acc = __builtin_amdgcn_mfma_f32_16x16x32_bf16(a1, wl8[ct * 128 + 64 + lane], acc, 0, 0, 0);
    u64 bm0 = __ballot(acc[0] <= t0);
    u64 bm1 = __ballot(acc[1] <= t1);
    u64 bm2 = __ballot(acc[2] <= t2);
    u64 bm3 = __ballot(acc[3] <= t3);
    if (lane < 4) {   // lane r owns reg r; ballot bit (q*16+n) -> pixel q*4+r, code ct*16+n
      u64 mk = (lane == 0) ? bm0 : (lane == 1) ? bm1 : (lane == 2) ? bm2 : bm3;
      int word = ct >> 2, sh = (ct & 3) * 16;
      #pragma unroll
      for (int q = 0; q < 4; ++q) {
        u64 bits = (mk >> (q * 16)) & 0xFFFFull;
        if (bits) candm[wv * 16 + q * 4 + lane][word] |= bits << sh;
      }
    }
  }
}

__device__ __forceinline__ void tile_refine(
    const float* __restrict__ xt, const float* __restrict__ w,
    const float* w2s, const float* Xs, const u64 (*candm)[8],
    int* sidx, float* __restrict__ out_idx, int bix, int tid, int lane) {
  const int px = tid >> 2, part = tid & 3;
  const float X = Xs[px];
  const float* xr = xt + px;
  float bestd = FLT_MAX; int bk = 1 << 30;
  for (int wd = part * 2; wd < part * 2 + 2; ++wd) {
    u64 msk = candm[px][wd];
    while (msk) {
      int bit = __ffsll((unsigned long long)msk) - 1;
      msk &= msk - 1;
      int k = wd * 64 + bit;
      const float* wp = w + k * DD;
      float P = 0.f;                       // ascending-d fma chain (BLAS order)
      #pragma unroll
      for (int dc = 0; dc < 16; ++dc) {
        nfloat4 w4 = *(const nfloat4*)(wp + dc * 4);
        P = __fmaf_rn(xr[(size_t)(dc * 4 + 0) * HW], w4[0], P);
        P = __fmaf_rn(xr[(size_t)(dc * 4 + 1) * HW], w4[1], P);
        P = __fmaf_rn(xr[(size_t)(dc * 4 + 2) * HW], w4[2], P);
        P = __fmaf_rn(xr[(size_t)(dc * 4 + 3) * HW], w4[3], P);
      }
      float dist = __fsub_rn(__fadd_rn(X, w2s[k]), __fadd_rn(P, P));
      if (dist < bestd || (dist == bestd && k < bk)) { bestd = dist; bk = k; }
    }
  }
  float od = __shfl_down(bestd, 1); int ok = __shfl_down(bk, 1);
  if ((lane & 3) < 3 && (od < bestd || (od == bestd && ok < bk))) { bestd = od; bk = ok; }
  od = __shfl_down(bestd, 2); ok = __shfl_down(bk, 2);
  if ((lane & 3) < 2 && (od < bestd || (od == bestd && ok < bk))) { bestd = od; bk = ok; }
  if (part == 0) {
    sidx[px] = bk;
    out_idx[bix * PXB + px] = (float)bk;
  }
}

__device__ __forceinline__ float tile_quant(
    const float* __restrict__ xt, const float* __restrict__ w,
    const int* sidx, float* __restrict__ qb, int tid) {
  float lsum = 0.f;
  for (int i = tid; i < PXB * DD; i += NTH) {   // 16 iters
    int d = i >> 7, pp = i & 127;
    float qv = w[sidx[pp] * DD + d];      // L1/L2-resident gather
    float dv = qv - xt[(size_t)d * HW + pp];
    lsum = __fmaf_rn(dv, dv, lsum);
    __builtin_nontemporal_store(qv, qb + (size_t)d * HW + pp);
  }
  return lsum;
}

__device__ __forceinline__ void tile_enc(
    const int* sidx, float* __restrict__ basep, int tid) {
  // fused one-hot enc (base ≡ 1 mod 4 floats: 3-head, aligned body, 1-tail)
  for (int t = tid; t < 16383; t += NTH) {
    int u = 3 + 4 * t;
    nfloat4 v;
    #pragma unroll
    for (int j = 0; j < 4; ++j) {
      int e = u + j;
      v[j] = (sidx[e >> 9] == (e & 511)) ? 1.0f : 0.0f;
    }
    __builtin_nontemporal_store(v, (nfloat4*)(basep + u));
  }
  if (tid < 3) basep[tid] = (sidx[0] == tid) ? 1.0f : 0.0f;
  else if (tid == 3) basep[PXB * KC - 1] = (sidx[127] == 511) ? 1.0f : 0.0f;
}

__device__ __forceinline__ void enc_zero_fill(float* __restrict__ basep, int tid) {
  // zero the 65536-float enc region (base ≡ 1 mod 4: 3-head, body, 1-tail)
  const nfloat4 z = {0.f, 0.f, 0.f, 0.f};
  if (tid < 3) __builtin_nontemporal_store(0.0f, basep + tid);
  else if (tid == 3) __builtin_nontemporal_store(0.0f, basep + PXB * KC - 1);
  for (int t = tid; t < 16383; t += NTH)
    __builtin_nontemporal_store(z, (nfloat4*)(basep + 3 + 4 * t));
}

// --- main R22 = exact R10 revert (best, 372.5 µs). R11's symmetrization
// regressed (+16): it doubled mode0's boundary burst past what screen-B can
// hide, and its post-refine-B full-drain re-serialized stores R10 left in
// flight until endpgm. Checkerboard axis is closed at the R10 schedule:
//   mode0: R4 schedule (fused enc at boundary/tail).
//   mode1: enc zeros up front (undrained, stream under screen-A/refine-A),
//          one full-drain post-refine-A (wait ~0), tiny scatters after.
__global__ __launch_bounds__(NTH, 4) void vq_fused(
    const float* __restrict__ x, const float* __restrict__ w,
    const float* __restrict__ w2g, const uint4* __restrict__ wswz,
    float* __restrict__ out_q, float* __restrict__ out_enc,
    float* __restrict__ out_idx, double* __restrict__ partial) {

  __shared__ uint4 wlds[4096];        // 64 KB: B-frags, slot=(ct*2+kc)*64+lane
  __shared__ float w2s[KC];           // 2 KB: np-exact ||w_k||^2
  __shared__ u64 candm[PXB][8];       // 8 KB: 512-bit candidate mask per pixel
  __shared__ float Xs[PXB];           // np-exact ||x||^2 per pixel
  __shared__ int sidx[PXB];
  __shared__ float sredf[8];

  const int tid = threadIdx.x;
  const int lane = tid & 63;
  const int wv = tid >> 6;            // wave 0..7, each owns 16 pixels
  const int mode = (blockIdx.x >> 8) & 1;   // co-resident pair {i, i+256} mixed

  // tile A = blockIdx.x, tile B = blockIdx.x + 512
  const int bix0 = blockIdx.x;
  const int b0 = bix0 >> 5;
  const int q0 = (bix0 & 31) * PXB;
  const float* xt0 = x + (size_t)b0 * (DD * HW) + q0;
  const int bix1 = blockIdx.x + NBLK;
  const int b1 = bix1 >> 5;
  const int q1 = (bix1 & 31) * PXB;
  const float* xt1 = x + (size_t)b1 * (DD * HW) + q1;
  float* bp0 = out_enc + (size_t)bix0 * (PXB * KC);
  float* bp1 = out_enc + (size_t)bix1 * (PXB * KC);

  // ---- stage prebuilt codebook ONCE (serves both tiles) ----
  #pragma unroll
  for (int s = 0; s < 8; ++s) wlds[tid + s * NTH] = wswz[tid + s * NTH];
  w2s[tid] = w2g[tid];   // KC == NTH

  short8 a0, a1;
  tile_prelude(xt0, Xs, candm, a0, a1, tid, lane, wv);
  if (mode) {            // mode1: front-load both tiles' enc zeros (in flight)
    enc_zero_fill(bp0, tid);
    enc_zero_fill(bp1, tid);
    barrier_lds_only();  // staging needs DS-visibility only; zeros NOT drained
  } else {
    __syncthreads();     // mode0: identical to R9 (nothing outstanding anyway)
  }

  const short8* wl8 = (const short8*)wlds;

  // ================= TILE A =================
  tile_screen(wl8, w2s, candm, a0, a1, lane, wv);
  barrier_lds_only();    // candm-A ready
  tile_refine(xt0, w, w2s, Xs, candm, sidx, out_idx, bix0, tid, lane);
  if (mode) {
    barrier_full_drain(); // zeros (both tiles) retired — drained in background
                          // under screen-A+refine-A; wait here ~0. Orders
                          // zeros before BOTH ones-scatters.
  } else {
    barrier_lds_only();   // sidx-A ready
  }

  // prelude-B FIRST (loads issue before the A-output store burst; overwrites
  // Xs/candm — safe, refine-A done; sidx untouched), then A outputs.
  tile_prelude(xt1, Xs, candm, a0, a1, tid, lane, wv);
  if (mode) {            // ones-scatter over drained zeros
    if (tid < PXB)
      __builtin_nontemporal_store(1.0f, bp0 + tid * KC + sidx[tid]);
  }
  {
    float lsum = tile_quant(xt0, w, sidx, out_q + (size_t)b0 * (DD * HW) + q0, tid);
    #pragma unroll
    for (int off = 32; off > 0; off >>= 1) lsum += __shfl_down(lsum, off);
    if (lane == 0) sredf[wv] = lsum;
  }
  if (!mode) tile_enc(sidx, bp0, tid);
  barrier_lds_only();    // sredf/Xs-B/candm-B ready; A stores stay in flight
  if (tid == 0) {
    double t = 0.0;
    #pragma unroll
    for (int i = 0; i < 8; ++i) t += (double)sredf[i];
    partial[bix0] = t;
  }

  // ================= TILE B =================
  tile_screen(wl8, w2s, candm, a0, a1, lane, wv);   // zero VMEM: A stores drain here
  barrier_lds_only();    // candm-B ready
  tile_refine(xt1, w, w2s, Xs, candm, sidx, out_idx, bix1, tid, lane);
  barrier_lds_only();    // sidx-B ready
  if (mode) {            // zeros-B already ordered by the post-refine-A drain
    if (tid < PXB)
      __builtin_nontemporal_store(1.0f, bp1 + tid * KC + sidx[tid]);
  }
  {
    float lsum = tile_quant(xt1, w, sidx, out_q + (size_t)b1 * (DD * HW) + q1, tid);
    #pragma unroll
    for (int off = 32; off > 0; off >>= 1) lsum += __shfl_down(lsum, off);
    if (lane == 0) sredf[wv] = lsum;
  }
  if (!mode) tile_enc(sidx, bp1, tid);
  barrier_lds_only();    // sredf-B ready
  if (tid == 0) {
    double t = 0.0;
    #pragma unroll
    for (int i = 0; i < 8; ++i) t += (double)sredf[i];
    partial[bix1] = t;
  }
  // kernel end: implicit full drain of tile-B stores
}

// --- epilogue: loss = vq + commit = 2 * mean((q - x)^2) ---
__global__ void finish_kernel(const double* __restrict__ partial,
                              float* __restrict__ out) {
  int t = threadIdx.x;   // 256 threads, 1024 partials
  double s = partial[t] + partial[t + 256] + partial[t + 512] + partial[t + 768];
  #pragma unroll
  for (int off = 32; off > 0; off >>= 1) s += __shfl_down(s, off);
  __shared__ double sr[4];
  if ((t & 63) == 0) sr[t >> 6] = s;
  __syncthreads();
  if (t == 0)
    out[0] = (float)(2.0 * (sr[0] + sr[1] + sr[2] + sr[3]) / (double)QSIZE);
}

extern "C" void kernel_launch(void* const* d_in, const int* in_sizes, int n_in,
                              void* d_out, int out_size, void* d_ws, size_t ws_size,
                              hipStream_t stream) {
  const float* x = (const float*)d_in[0];   // [32,64,64,64] f32 NCHW
  const float* w = (const float*)d_in[1];   // [512,64] f32
  float* out = (float*)d_out;
  float* out_q = out + 1;
  float* out_enc = out_q + QSIZE;
  float* out_idx = out_enc + (size_t)NPIX * KC;

  // d_ws layout: partial[1024] @0 (8 KB) | w2g[512] @8192 | wswz[4096] @16384
  double* partial = (double*)d_ws;
  float* w2g = (float*)((char*)d_ws + 8192);
  uint4* wswz = (uint4*)((char*)d_ws + 16384);

  prep<<<4, 1024, 0, stream>>>(w, w2g, wswz);
  vq_fused<<<NBLK, NTH, 0, stream>>>(x, w, w2g, wswz, out_q, out_enc, out_idx, partial);
  finish_kernel<<<1, 256, 0, stream>>>(partial, out);
}